// Round 23
// baseline (523.745 us; speedup 1.0000x reference)
//
#include <hip/hip_runtime.h>
#include <hip/hip_fp16.h>
#include <stdint.h>

#define LATF 256
#define NT 119
#define NNODES 100000
#define NEDGES 400000
#define K3_BLOCKS 12500
#define K2_BLOCKS 1563

typedef __attribute__((ext_vector_type(8))) short short8;
typedef __attribute__((ext_vector_type(4))) short s4v;
typedef __attribute__((ext_vector_type(8))) _Float16 half8;
typedef __attribute__((ext_vector_type(4))) _Float16 h4v;
typedef __attribute__((ext_vector_type(4))) float f4;

__device__ __forceinline__ short f2h(float f) {
  _Float16 h = (_Float16)f;                    // RNE
  return *reinterpret_cast<short*>(&h);
}

// ---------------- prep: cast + transposed weights (fp16) + Wpos ----------------
__global__ __launch_bounds__(256) void prep_kernel(
    const float* __restrict__ lat, const float* __restrict__ pos,
    const float* __restrict__ nW1, const float* __restrict__ tW1, const float* __restrict__ dW1,
    const float* __restrict__ nW2, const float* __restrict__ tW2, const float* __restrict__ dW2,
    const float* __restrict__ nW3, const float* __restrict__ tW3, const float* __restrict__ dW3,
    const float* __restrict__ nb1, const float* __restrict__ tb1, const float* __restrict__ db1,
    short* __restrict__ latent_hf, short* __restrict__ pos_hf,
    short* __restrict__ Wtcat, short* __restrict__ Wt2cat,
    short* __restrict__ Wt3n, short* __restrict__ Wt3t, short* __restrict__ Wt3d,
    short* __restrict__ Wpos)
{
  int i = blockIdx.x * 256 + threadIdx.x;
  if (i < 524288) { latent_hf[i] = f2h(lat[i]); return; }
  i -= 524288;
  if (i < 800000) { pos_hf[i] = f2h(pos[i]); return; }
  i -= 800000;
  if (i < 1280 * 288) {               // Wtcat[n][k], n-major, K padded 264->288
    int n = i / 288, k = i % 288;
    float v = 0.f;
    if (k < 264) {
      if (n < 256)       v = nW1[k * 256 + n];
      else if (n < 512)  v = tW1[k * 256 + (n - 256)];
      else if (n < 768)  v = tW1[(264 + k) * 256 + (n - 512)];
      else if (n < 1024) v = dW1[k * 256 + (n - 768)];
      else               v = dW1[(264 + k) * 256 + (n - 1024)];
    } else if (k == 264) {            // bias row (k1 h1_node path)
      if (n < 256)        v = nb1[n];
      else if (n < 512)   v = tb1[n - 256];
      else if (n >= 768 && n < 1024) v = db1[n - 768];
    }
    Wtcat[n * 288 + k] = f2h(v);
    return;
  }
  i -= 1280 * 288;
  if (i < 384 * 256) {                // Wt2cat[n][k]: rows 0-127 nW2, 128-255 tW2, 256-383 dW2
    int n = i / 256, k = i % 256;
    float v = (n < 128) ? nW2[k * 128 + n] : (n < 256) ? tW2[k * 128 + (n - 128)]
                                                       : dW2[k * 128 + (n - 256)];
    Wt2cat[n * 256 + k] = f2h(v);
    return;
  }
  i -= 384 * 256;
  if (i < 128 * 128) {                // Wt3n[n][k], n padded 119->128
    int n = i / 128, k = i % 128;
    Wt3n[i] = (n < NT) ? f2h(nW3[k * NT + n]) : (short)0;
    return;
  }
  i -= 128 * 128;
  if (i < 4 * 128) { int n = i / 128, k = i % 128; Wt3t[i] = f2h(tW3[k * 4 + n]); return; }
  i -= 512;
  if (i < 3 * 128) { int n = i / 128, k = i % 128; Wt3d[i] = f2h(dW3[k * 3 + n]); return; }
  i -= 384;
  if (i < 512 * 32) {                 // Wpos[n][32]: k<8 pos_src, k in [8,16) pos_dst, k==16 bias
    int n = i >> 5, k = i & 31;
    const float* W = (n < 256) ? tW1 : dW1;
    const float* b = (n < 256) ? tb1 : db1;
    const int c = n & 255;
    float v = 0.f;
    if (k < 8)        v = W[(256 + k) * 256 + c];
    else if (k < 16)  v = W[(520 + (k - 8)) * 256 + c];
    else if (k == 16) v = b[c];
    Wpos[n * 32 + k] = f2h(v);
    return;
  }
}

// ---------------- kge: edge -> graph index tables + pre-gathered pos rows ----------------
__global__ __launch_bounds__(256) void kge(
    const int* __restrict__ eidx, const int* __restrict__ batch,
    const short* __restrict__ pos_hf,
    int* __restrict__ ges, int* __restrict__ ged,
    short* __restrict__ poseS, short* __restrict__ poseD)
{
  int e = blockIdx.x * 256 + threadIdx.x;
  if (e < NEDGES) {
    const int s = eidx[e];
    const int d = eidx[NEDGES + e];
    ges[e] = batch[s];
    ged[e] = batch[d];
    *(short8*)(poseS + (size_t)e * 8) = *(const short8*)(pos_hf + (size_t)s * 8);
    *(short8*)(poseD + (size_t)e * 8) = *(const short8*)(pos_hf + (size_t)d * 8);
  }
}

// ---------------- kG: per-graph latent projections (2048 x 1024, L2-resident) ----------------
__global__ __launch_bounds__(256) void kG(
    const short* __restrict__ latent_hf, const short* __restrict__ Wtcat,
    short* __restrict__ G)
{
  __shared__ short Hs[64 * 140];
  const int t = threadIdx.x;
  const int bm0 = blockIdx.x * 64;             // 32 blocks -> 2048 rows
  const int y = blockIdx.y;                    // 0..7
  const int wid = t >> 6, lane = t & 63;
  const int wm = wid >> 1, wn = wid & 1;
  const int lrow = lane & 15, kq = lane >> 4;

  const int row0 = bm0 + wm * 32 + lrow;
  const int row1 = row0 + 16;

  f4 acc[2][4];
  #pragma unroll
  for (int a = 0; a < 2; ++a)
    #pragma unroll
    for (int b = 0; b < 4; ++b) acc[a][b] = (f4){0.f, 0.f, 0.f, 0.f};

  #pragma unroll
  for (int kc = 0; kc < 8; ++kc) {
    half8 a0 = *(const half8*)(latent_hf + row0 * 256 + kc * 32 + kq * 8);
    half8 a1 = *(const half8*)(latent_hf + row1 * 256 + kc * 32 + kq * 8);
    #pragma unroll
    for (int nf = 0; nf < 4; ++nf) {
      const int ncol = 256 + y * 128 + wn * 64 + nf * 16 + lrow;
      half8 bfv = *(const half8*)(Wtcat + ncol * 288 + kc * 32 + kq * 8);
      acc[0][nf] = __builtin_amdgcn_mfma_f32_16x16x32_f16(a0, bfv, acc[0][nf], 0, 0, 0);
      acc[1][nf] = __builtin_amdgcn_mfma_f32_16x16x32_f16(a1, bfv, acc[1][nf], 0, 0, 0);
    }
  }

  #pragma unroll
  for (int mf = 0; mf < 2; ++mf)
    #pragma unroll
    for (int nf = 0; nf < 4; ++nf) {
      const int ncol = wn * 64 + nf * 16 + lrow;
      #pragma unroll
      for (int r = 0; r < 4; ++r) {
        const int mrow = wm * 32 + mf * 16 + kq * 4 + r;
        Hs[mrow * 140 + ncol] = f2h(acc[mf][nf][r]);
      }
    }
  __syncthreads();

  {
    const int cb[8] = {0, 128, 512, 640, 256, 384, 768, 896};  // col permute per slab
    const int row = t >> 2, cc = (t & 3) * 32;
    short* outp = G + (size_t)(bm0 + row) * 1024 + cb[y];
    #pragma unroll
    for (int c4 = 0; c4 < 4; ++c4) {
      short8 v = *(const short8*)(Hs + row * 140 + cc + c4 * 8);
      *(short8*)(outp + cc + c4 * 8) = v;
    }
  }
}

// ---------------- K1 (R16-proven): h1_node only, LDS-free direct-A ----------------
__global__ __launch_bounds__(256) void k1_gemm(
    const short* __restrict__ latent_hf, const short* __restrict__ pos_hf,
    const int* __restrict__ batch, const short* __restrict__ Wtcat,
    short* __restrict__ h1_node)
{
  __shared__ short Hs[64 * 140];
  const int t = threadIdx.x;
  const int bm0 = blockIdx.x * 64;
  const int y = blockIdx.y;                    // 0,1
  const int n0 = y * 128;
  const int wid = t >> 6, lane = t & 63;
  const int wm = wid >> 1, wn = wid & 1;
  const int lrow = lane & 15, kq = lane >> 4;
  const half8 hz = {0, 0, 0, 0, 0, 0, 0, 0};

  const int row0 = bm0 + wm * 32 + lrow;
  const int row1 = row0 + 16;
  const int g0 = (row0 < NNODES) ? batch[row0] : 0;
  const int g1 = (row1 < NNODES) ? batch[row1] : 0;

  f4 acc[2][4];
  #pragma unroll
  for (int a = 0; a < 2; ++a)
    #pragma unroll
    for (int b = 0; b < 4; ++b) acc[a][b] = (f4){0.f, 0.f, 0.f, 0.f};

  #pragma unroll
  for (int kc = 0; kc < 9; ++kc) {
    half8 a0, a1;
    if (kc < 8) {
      a0 = *(const half8*)(latent_hf + g0 * 256 + kc * 32 + kq * 8);
      a1 = *(const half8*)(latent_hf + g1 * 256 + kc * 32 + kq * 8);
    } else {
      a0 = hz; a1 = hz;
      if (kq == 0) {
        if (row0 < NNODES) a0 = *(const half8*)(pos_hf + row0 * 8);
        if (row1 < NNODES) a1 = *(const half8*)(pos_hf + row1 * 8);
      } else if (kq == 1) {
        a0[0] = (_Float16)1.0f;
        a1[0] = (_Float16)1.0f;
      }
    }
    #pragma unroll
    for (int nf = 0; nf < 4; ++nf) {
      const int ncol = n0 + wn * 64 + nf * 16 + lrow;
      half8 bfv = *(const half8*)(Wtcat + ncol * 288 + kc * 32 + kq * 8);
      acc[0][nf] = __builtin_amdgcn_mfma_f32_16x16x32_f16(a0, bfv, acc[0][nf], 0, 0, 0);
      acc[1][nf] = __builtin_amdgcn_mfma_f32_16x16x32_f16(a1, bfv, acc[1][nf], 0, 0, 0);
    }
  }

  #pragma unroll
  for (int mf = 0; mf < 2; ++mf)
    #pragma unroll
    for (int nf = 0; nf < 4; ++nf) {
      const int ncol = wn * 64 + nf * 16 + lrow;
      #pragma unroll
      for (int r = 0; r < 4; ++r) {
        const int mrow = wm * 32 + mf * 16 + kq * 4 + r;
        float v = acc[mf][nf][r];
        if (v < 0.f) v = 0.f;
        Hs[mrow * 140 + ncol] = f2h(v);
      }
    }
  __syncthreads();

  {
    const int row = t >> 2, cc = (t & 3) * 32;
    const int m = bm0 + row;
    if (m < NNODES) {
      short* outp = h1_node + (size_t)m * 256 + y * 128;
      #pragma unroll
      for (int c4 = 0; c4 < 4; ++c4) {
        short8 v = *(const short8*)(Hs + row * 140 + cc + c4 * 8);
        *(short8*)(outp + cc + c4 * 8) = v;
      }
    }
  }
}

// ---------------- K23: fused h1-build (swapped pos-MFMA + direct-G reads); k2 unchanged ----------------
// k3 h1 build: operand-swapped pos MFMA puts lane = (edge=lrow, wcols kq*4..+3);
// the lane loads its 4 G cols (8B each) for src/dst, fuses pa+Gs+Gd+relu in regs,
// writes one b64 per (eh,nf). No pos LDS round-trip, no separate combine, 4 barriers.
__global__ __launch_bounds__(256) void k23_fused(
    const short* __restrict__ G,
    const int* __restrict__ ges, const int* __restrict__ ged,
    const short* __restrict__ poseS, const short* __restrict__ poseD,
    const short* __restrict__ Wpos,
    const short* __restrict__ Wt2cat, const short* __restrict__ Wt3t, const short* __restrict__ Wt3d,
    const float* __restrict__ tb2, const float* __restrict__ tb3,
    const float* __restrict__ db2, const float* __restrict__ db3,
    float* __restrict__ out_t, float* __restrict__ out_d,
    const short* __restrict__ h1_node, const short* __restrict__ Wt3n,
    const float* __restrict__ nb2, const float* __restrict__ nb3,
    float* __restrict__ out_node)
{
  __shared__ short smem[32 * 520];             // 33,280 B
  const int t = threadIdx.x;
  const int wid = t >> 6, lane = t & 63;
  const int lrow = lane & 15, kq = lane >> 4;
  const half8 hz = {0, 0, 0, 0, 0, 0, 0, 0};

  const int grp = blockIdx.x / 9, rem = blockIdx.x % 9;

  if (rem != 8) {
    // ================= k3: edge tail =================
    const int tile = grp * 8 + rem;
    if (tile >= K3_BLOCKS) return;
    short* h1 = smem;
    const int e0 = tile * 32;

    // per-lane edges (C col = lrow); two 16-edge halves
    const int eA = e0 + lrow, eB = e0 + 16 + lrow;
    const int sgA = ges[eA], dgA = ged[eA];
    const int sgB = ges[eB], dgB = ged[eB];

    // B-frags: pos vectors [pos_s(8) | pos_d(8) | 1 | 0...] selected by kq
    half8 pvA = hz, pvB = hz;
    if (kq == 0)      { pvA = *(const half8*)(poseS + (size_t)eA * 8);
                        pvB = *(const half8*)(poseS + (size_t)eB * 8); }
    else if (kq == 1) { pvA = *(const half8*)(poseD + (size_t)eA * 8);
                        pvB = *(const half8*)(poseD + (size_t)eB * 8); }
    else if (kq == 2) { pvA[0] = (_Float16)1.0f; pvB[0] = (_Float16)1.0f; }

    #pragma unroll
    for (int nf = 0; nf < 8; ++nf) {
      const int colb = wid * 128 + nf * 16;          // 16-wcol block base
      const int wcb = colb + kq * 4;                 // this lane's 4 wcols
      half8 wf = *(const half8*)(Wpos + (colb + lrow) * 32 + kq * 8);  // A-frag (row=lrow)
      // eh = 0
      {
        f4 pa = (f4){0.f, 0.f, 0.f, 0.f};
        pa = __builtin_amdgcn_mfma_f32_16x16x32_f16(wf, pvA, pa, 0, 0, 0);
        s4v gs = *(const s4v*)(G + (size_t)sgA * 1024 + wcb);
        s4v gd = *(const s4v*)(G + (size_t)dgA * 1024 + 512 + wcb);
        h4v ga = __builtin_bit_cast(h4v, gs);
        h4v gb = __builtin_bit_cast(h4v, gd);
        s4v o;
        #pragma unroll
        for (int x = 0; x < 4; ++x) {
          float h = pa[x] + (float)ga[x] + (float)gb[x];
          o[x] = f2h(h > 0.f ? h : 0.f);
        }
        *(s4v*)(h1 + lrow * 520 + wcb) = o;
      }
      // eh = 1
      {
        f4 pa = (f4){0.f, 0.f, 0.f, 0.f};
        pa = __builtin_amdgcn_mfma_f32_16x16x32_f16(wf, pvB, pa, 0, 0, 0);
        s4v gs = *(const s4v*)(G + (size_t)sgB * 1024 + wcb);
        s4v gd = *(const s4v*)(G + (size_t)dgB * 1024 + 512 + wcb);
        h4v ga = __builtin_bit_cast(h4v, gs);
        h4v gb = __builtin_bit_cast(h4v, gd);
        s4v o;
        #pragma unroll
        for (int x = 0; x < 4; ++x) {
          float h = pa[x] + (float)ga[x] + (float)gb[x];
          o[x] = f2h(h > 0.f ? h : 0.f);
        }
        *(s4v*)(h1 + (16 + lrow) * 520 + wcb) = o;
      }
    }
    __syncthreads();                           // h1 ready

    // ---- layer2 TYPE ----
    f4 acc_t[2][2];
    #pragma unroll
    for (int a = 0; a < 2; ++a)
      #pragma unroll
      for (int b = 0; b < 2; ++b) acc_t[a][b] = (f4){0.f, 0.f, 0.f, 0.f};
    #pragma unroll
    for (int kc = 0; kc < 8; ++kc) {
      half8 a0 = *(const half8*)(h1 + lrow * 520 + kc * 32 + kq * 8);
      half8 a1 = *(const half8*)(h1 + (16 + lrow) * 520 + kc * 32 + kq * 8);
      #pragma unroll
      for (int nf = 0; nf < 2; ++nf) {
        half8 bfv = *(const half8*)(Wt2cat + (128 + wid * 32 + nf * 16 + lrow) * 256 + kc * 32 + kq * 8);
        acc_t[0][nf] = __builtin_amdgcn_mfma_f32_16x16x32_f16(a0, bfv, acc_t[0][nf], 0, 0, 0);
        acc_t[1][nf] = __builtin_amdgcn_mfma_f32_16x16x32_f16(a1, bfv, acc_t[1][nf], 0, 0, 0);
      }
    }
    __syncthreads();

    // ---- h2_t -> cols 0:128 ----
    #pragma unroll
    for (int mf = 0; mf < 2; ++mf)
      #pragma unroll
      for (int nf = 0; nf < 2; ++nf) {
        const int n2 = wid * 32 + nf * 16 + lrow;
        const float bb = tb2[n2];
        #pragma unroll
        for (int rr = 0; rr < 4; ++rr) {
          float h = acc_t[mf][nf][rr] + bb;
          h1[(mf * 16 + kq * 4 + rr) * 520 + n2] = f2h(h > 0.f ? h : 0.f);
        }
      }

    // ---- layer2 DIR ----
    f4 acc_d[2][2];
    #pragma unroll
    for (int a = 0; a < 2; ++a)
      #pragma unroll
      for (int b = 0; b < 2; ++b) acc_d[a][b] = (f4){0.f, 0.f, 0.f, 0.f};
    #pragma unroll
    for (int kc = 0; kc < 8; ++kc) {
      half8 a0 = *(const half8*)(h1 + lrow * 520 + 256 + kc * 32 + kq * 8);
      half8 a1 = *(const half8*)(h1 + (16 + lrow) * 520 + 256 + kc * 32 + kq * 8);
      #pragma unroll
      for (int nf = 0; nf < 2; ++nf) {
        half8 bfv = *(const half8*)(Wt2cat + (256 + wid * 32 + nf * 16 + lrow) * 256 + kc * 32 + kq * 8);
        acc_d[0][nf] = __builtin_amdgcn_mfma_f32_16x16x32_f16(a0, bfv, acc_d[0][nf], 0, 0, 0);
        acc_d[1][nf] = __builtin_amdgcn_mfma_f32_16x16x32_f16(a1, bfv, acc_d[1][nf], 0, 0, 0);
      }
    }

    // ---- h2_d -> cols 128:256 ----
    #pragma unroll
    for (int mf = 0; mf < 2; ++mf)
      #pragma unroll
      for (int nf = 0; nf < 2; ++nf) {
        const int n2 = wid * 32 + nf * 16 + lrow;
        const float bb = db2[n2];
        #pragma unroll
        for (int rr = 0; rr < 4; ++rr) {
          float h = acc_d[mf][nf][rr] + bb;
          h1[(mf * 16 + kq * 4 + rr) * 520 + 128 + n2] = f2h(h > 0.f ? h : 0.f);
        }
      }
    __syncthreads();

    // ---- layer 3 via MFMA ----
    {
      const int mlp3 = wid >> 1, mh = wid & 1;
      const int ncols = mlp3 ? 3 : 4;
      const short* W3 = mlp3 ? Wt3d : Wt3t;
      f4 acc3 = (f4){0.f, 0.f, 0.f, 0.f};
      #pragma unroll
      for (int kc = 0; kc < 4; ++kc) {
        half8 af = *(const half8*)(h1 + (mh * 16 + lrow) * 520 + mlp3 * 128 + kc * 32 + kq * 8);
        half8 bfv = hz;
        if (lrow < ncols) bfv = *(const half8*)(W3 + lrow * 128 + kc * 32 + kq * 8);
        acc3 = __builtin_amdgcn_mfma_f32_16x16x32_f16(af, bfv, acc3, 0, 0, 0);
      }
      if (lrow < ncols) {
        const float bb = (mlp3 ? db3 : tb3)[lrow];
        float* outp = mlp3 ? out_d : out_t;
        #pragma unroll
        for (int r = 0; r < 4; ++r) {
          const int e = e0 + mh * 16 + kq * 4 + r;
          outp[(size_t)e * ncols + lrow] = acc3[r] + bb;
        }
      }
    }
  } else {
    // ================= k2: node tail (unchanged) =================
    short* h2s = smem;
    const int bm0 = grp * 64;
    const int wm = wid >> 1, wn = wid & 1;

    f4 acc[2][4];
    #pragma unroll
    for (int a = 0; a < 2; ++a)
      #pragma unroll
      for (int b = 0; b < 4; ++b) acc[a][b] = (f4){0.f, 0.f, 0.f, 0.f};

    #pragma unroll
    for (int kc = 0; kc < 8; ++kc) {
      half8 af[2];
      #pragma unroll
      for (int mf = 0; mf < 2; ++mf) {
        const int m = bm0 + wm * 32 + mf * 16 + lrow;
        if (m < NNODES) af[mf] = *(const half8*)(h1_node + m * 256 + kc * 32 + kq * 8);
        else            af[mf] = (half8){0, 0, 0, 0, 0, 0, 0, 0};
      }
      #pragma unroll
      for (int nf = 0; nf < 4; ++nf) {
        const int ncol = wn * 64 + nf * 16 + lrow;
        half8 bfv = *(const half8*)(Wt2cat + ncol * 256 + kc * 32 + kq * 8);
        acc[0][nf] = __builtin_amdgcn_mfma_f32_16x16x32_f16(af[0], bfv, acc[0][nf], 0, 0, 0);
        acc[1][nf] = __builtin_amdgcn_mfma_f32_16x16x32_f16(af[1], bfv, acc[1][nf], 0, 0, 0);
      }
    }
    #pragma unroll
    for (int mf = 0; mf < 2; ++mf)
      #pragma unroll
      for (int nf = 0; nf < 4; ++nf) {
        const int n = wn * 64 + nf * 16 + lrow;
        #pragma unroll
        for (int r = 0; r < 4; ++r) {
          const int ml = wm * 32 + mf * 16 + kq * 4 + r;
          float h = acc[mf][nf][r] + nb2[n];
          h2s[ml * 136 + n] = f2h(h > 0.f ? h : 0.f);
        }
      }
    __syncthreads();

    f4 acc2[2][4];
    #pragma unroll
    for (int a = 0; a < 2; ++a)
      #pragma unroll
      for (int b = 0; b < 4; ++b) acc2[a][b] = (f4){0.f, 0.f, 0.f, 0.f};

    #pragma unroll
    for (int kc = 0; kc < 4; ++kc) {
      half8 af[2];
      #pragma unroll
      for (int mf = 0; mf < 2; ++mf)
        af[mf] = *(const half8*)(h2s + (wm * 32 + mf * 16 + lrow) * 136 + kc * 32 + kq * 8);
      #pragma unroll
      for (int nf = 0; nf < 4; ++nf) {
        const int ncol = wn * 64 + nf * 16 + lrow;
        half8 bfv = *(const half8*)(Wt3n + ncol * 128 + kc * 32 + kq * 8);
        acc2[0][nf] = __builtin_amdgcn_mfma_f32_16x16x32_f16(af[0], bfv, acc2[0][nf], 0, 0, 0);
        acc2[1][nf] = __builtin_amdgcn_mfma_f32_16x16x32_f16(af[1], bfv, acc2[1][nf], 0, 0, 0);
      }
    }
    #pragma unroll
    for (int mf = 0; mf < 2; ++mf)
      #pragma unroll
      for (int nf = 0; nf < 4; ++nf) {
        const int n = wn * 64 + nf * 16 + lrow;
        #pragma unroll
        for (int r = 0; r < 4; ++r) {
          const int m = bm0 + wm * 32 + mf * 16 + kq * 4 + r;
          if (m < NNODES && n < NT) out_node[m * NT + n] = acc2[mf][nf][r] + nb3[n];
        }
      }
  }
}

extern "C" void kernel_launch(void* const* d_in, const int* in_sizes, int n_in,
                              void* d_out, int out_size, void* d_ws, size_t ws_size,
                              hipStream_t stream)
{
  const float* lat = (const float*)d_in[0];
  const float* pos = (const float*)d_in[1];
  const int* batch = (const int*)d_in[2];
  const int* eidx  = (const int*)d_in[3];
  const float* nW1 = (const float*)d_in[4];  const float* nb1 = (const float*)d_in[5];
  const float* nW2 = (const float*)d_in[6];  const float* nb2 = (const float*)d_in[7];
  const float* nW3 = (const float*)d_in[8];  const float* nb3 = (const float*)d_in[9];
  const float* tW1 = (const float*)d_in[10]; const float* tb1 = (const float*)d_in[11];
  const float* tW2 = (const float*)d_in[12]; const float* tb2 = (const float*)d_in[13];
  const float* tW3 = (const float*)d_in[14]; const float* tb3 = (const float*)d_in[15];
  const float* dW1 = (const float*)d_in[16]; const float* db1 = (const float*)d_in[17];
  const float* dW2 = (const float*)d_in[18]; const float* db2 = (const float*)d_in[19];
  const float* dW3 = (const float*)d_in[20]; const float* db3 = (const float*)d_in[21];

  char* ws = (char*)d_ws;
  short* latent_hf = (short*)(ws + 0);          //  1,048,576 B
  short* pos_hf    = (short*)(ws + 1048576);    //  1,600,000 B
  short* Wtcat     = (short*)(ws + 2648576);    //    737,280 B
  short* Wt2cat    = (short*)(ws + 3385856);    //    196,608 B
  short* Wt3n      = (short*)(ws + 3582464);    //     32,768 B
  short* Wt3t      = (short*)(ws + 3615232);    //      1,024 B
  short* Wt3d      = (short*)(ws + 3616256);    //      1,024 B
  short* Wpos      = (short*)(ws + 3617280);    //     32,768 B
  short* h1_node   = (short*)(ws + 3650048);    // 51,200,000 B
  int*   ges       = (int*)(ws + 54850048);     //  1,600,000 B
  int*   ged       = (int*)(ws + 56450048);     //  1,600,000 B
  short* G         = (short*)(ws + 58050048);   //  4,194,304 B
  short* poseS     = (short*)(ws + 62244352);   //  6,400,000 B
  short* poseD     = (short*)(ws + 68644352);   //  6,400,000 B -> total ~75.0 MB

  float* out_node = (float*)d_out;
  float* out_t = out_node + (size_t)NNODES * NT;
  float* out_d = out_t + (size_t)NEDGES * 4;

  prep_kernel<<<7129, 256, 0, stream>>>(lat, pos, nW1, tW1, dW1, nW2, tW2, dW2,
                                        nW3, tW3, dW3, nb1, tb1, db1,
                                        latent_hf, pos_hf, Wtcat,
                                        Wt2cat, Wt3n, Wt3t, Wt3d, Wpos);
  kge<<<1563, 256, 0, stream>>>(eidx, batch, pos_hf, ges, ged, poseS, poseD);
  kG<<<dim3(32, 8), 256, 0, stream>>>(latent_hf, Wtcat, G);
  k1_gemm<<<dim3(1563, 2), 256, 0, stream>>>(latent_hf, pos_hf, batch, Wtcat, h1_node);
  k23_fused<<<K2_BLOCKS * 9, 256, 0, stream>>>(
      G, ges, ged, poseS, poseD, Wpos, Wt2cat, Wt3t, Wt3d, tb2, tb3, db2, db3,
      out_t, out_d, h1_node, Wt3n, nb2, nb3, out_node);
}

// Round 24
// 399.045 us; speedup vs baseline: 1.3125x; 1.3125x over previous
//
#include <hip/hip_runtime.h>
#include <hip/hip_fp16.h>
#include <stdint.h>

#define LATF 256
#define NT 119
#define NNODES 100000
#define NEDGES 400000
#define K3_BLOCKS 12500
#define K2_BLOCKS 1563

typedef __attribute__((ext_vector_type(8))) short short8;
typedef __attribute__((ext_vector_type(8))) _Float16 half8;
typedef __attribute__((ext_vector_type(4))) float f4;

__device__ __forceinline__ short f2h(float f) {
  _Float16 h = (_Float16)f;                    // RNE
  return *reinterpret_cast<short*>(&h);
}

// ---------------- prep: cast + transposed weights (fp16) + Wpos ----------------
__global__ __launch_bounds__(256) void prep_kernel(
    const float* __restrict__ lat, const float* __restrict__ pos,
    const float* __restrict__ nW1, const float* __restrict__ tW1, const float* __restrict__ dW1,
    const float* __restrict__ nW2, const float* __restrict__ tW2, const float* __restrict__ dW2,
    const float* __restrict__ nW3, const float* __restrict__ tW3, const float* __restrict__ dW3,
    const float* __restrict__ nb1, const float* __restrict__ tb1, const float* __restrict__ db1,
    short* __restrict__ latent_hf, short* __restrict__ pos_hf,
    short* __restrict__ Wtcat, short* __restrict__ Wt2cat,
    short* __restrict__ Wt3n, short* __restrict__ Wt3t, short* __restrict__ Wt3d,
    short* __restrict__ Wpos)
{
  int i = blockIdx.x * 256 + threadIdx.x;
  if (i < 524288) { latent_hf[i] = f2h(lat[i]); return; }
  i -= 524288;
  if (i < 800000) { pos_hf[i] = f2h(pos[i]); return; }
  i -= 800000;
  if (i < 1280 * 288) {               // Wtcat[n][k], n-major, K padded 264->288
    int n = i / 288, k = i % 288;
    float v = 0.f;
    if (k < 264) {
      if (n < 256)       v = nW1[k * 256 + n];
      else if (n < 512)  v = tW1[k * 256 + (n - 256)];
      else if (n < 768)  v = tW1[(264 + k) * 256 + (n - 512)];
      else if (n < 1024) v = dW1[k * 256 + (n - 768)];
      else               v = dW1[(264 + k) * 256 + (n - 1024)];
    } else if (k == 264) {            // bias row (k1 h1_node path)
      if (n < 256)        v = nb1[n];
      else if (n < 512)   v = tb1[n - 256];
      else if (n >= 768 && n < 1024) v = db1[n - 768];
    }
    Wtcat[n * 288 + k] = f2h(v);
    return;
  }
  i -= 1280 * 288;
  if (i < 384 * 256) {                // Wt2cat[n][k]: rows 0-127 nW2, 128-255 tW2, 256-383 dW2
    int n = i / 256, k = i % 256;
    float v = (n < 128) ? nW2[k * 128 + n] : (n < 256) ? tW2[k * 128 + (n - 128)]
                                                       : dW2[k * 128 + (n - 256)];
    Wt2cat[n * 256 + k] = f2h(v);
    return;
  }
  i -= 384 * 256;
  if (i < 128 * 128) {                // Wt3n[n][k], n padded 119->128
    int n = i / 128, k = i % 128;
    Wt3n[i] = (n < NT) ? f2h(nW3[k * NT + n]) : (short)0;
    return;
  }
  i -= 128 * 128;
  if (i < 4 * 128) { int n = i / 128, k = i % 128; Wt3t[i] = f2h(tW3[k * 4 + n]); return; }
  i -= 512;
  if (i < 3 * 128) { int n = i / 128, k = i % 128; Wt3d[i] = f2h(dW3[k * 3 + n]); return; }
  i -= 384;
  if (i < 512 * 32) {                 // Wpos[n][32]: k<8 pos_src, k in [8,16) pos_dst, k==16 bias
    int n = i >> 5, k = i & 31;
    const float* W = (n < 256) ? tW1 : dW1;
    const float* b = (n < 256) ? tb1 : db1;
    const int c = n & 255;
    float v = 0.f;
    if (k < 8)        v = W[(256 + k) * 256 + c];
    else if (k < 16)  v = W[(520 + (k - 8)) * 256 + c];
    else if (k == 16) v = b[c];
    Wpos[n * 32 + k] = f2h(v);
    return;
  }
}

// ---------------- kge: edge -> graph index tables + pre-gathered pos rows ----------------
__global__ __launch_bounds__(256) void kge(
    const int* __restrict__ eidx, const int* __restrict__ batch,
    const short* __restrict__ pos_hf,
    int* __restrict__ ges, int* __restrict__ ged,
    short* __restrict__ poseS, short* __restrict__ poseD)
{
  int e = blockIdx.x * 256 + threadIdx.x;
  if (e < NEDGES) {
    const int s = eidx[e];
    const int d = eidx[NEDGES + e];
    ges[e] = batch[s];
    ged[e] = batch[d];
    *(short8*)(poseS + (size_t)e * 8) = *(const short8*)(pos_hf + (size_t)s * 8);
    *(short8*)(poseD + (size_t)e * 8) = *(const short8*)(pos_hf + (size_t)d * 8);
  }
}

// ---------------- kG: per-graph latent projections (2048 x 1024, L2-resident) ----------------
__global__ __launch_bounds__(256) void kG(
    const short* __restrict__ latent_hf, const short* __restrict__ Wtcat,
    short* __restrict__ G)
{
  __shared__ short Hs[64 * 140];
  const int t = threadIdx.x;
  const int bm0 = blockIdx.x * 64;             // 32 blocks -> 2048 rows
  const int y = blockIdx.y;                    // 0..7
  const int wid = t >> 6, lane = t & 63;
  const int wm = wid >> 1, wn = wid & 1;
  const int lrow = lane & 15, kq = lane >> 4;

  const int row0 = bm0 + wm * 32 + lrow;
  const int row1 = row0 + 16;

  f4 acc[2][4];
  #pragma unroll
  for (int a = 0; a < 2; ++a)
    #pragma unroll
    for (int b = 0; b < 4; ++b) acc[a][b] = (f4){0.f, 0.f, 0.f, 0.f};

  #pragma unroll
  for (int kc = 0; kc < 8; ++kc) {
    half8 a0 = *(const half8*)(latent_hf + row0 * 256 + kc * 32 + kq * 8);
    half8 a1 = *(const half8*)(latent_hf + row1 * 256 + kc * 32 + kq * 8);
    #pragma unroll
    for (int nf = 0; nf < 4; ++nf) {
      const int ncol = 256 + y * 128 + wn * 64 + nf * 16 + lrow;
      half8 bfv = *(const half8*)(Wtcat + ncol * 288 + kc * 32 + kq * 8);
      acc[0][nf] = __builtin_amdgcn_mfma_f32_16x16x32_f16(a0, bfv, acc[0][nf], 0, 0, 0);
      acc[1][nf] = __builtin_amdgcn_mfma_f32_16x16x32_f16(a1, bfv, acc[1][nf], 0, 0, 0);
    }
  }

  #pragma unroll
  for (int mf = 0; mf < 2; ++mf)
    #pragma unroll
    for (int nf = 0; nf < 4; ++nf) {
      const int ncol = wn * 64 + nf * 16 + lrow;
      #pragma unroll
      for (int r = 0; r < 4; ++r) {
        const int mrow = wm * 32 + mf * 16 + kq * 4 + r;
        Hs[mrow * 140 + ncol] = f2h(acc[mf][nf][r]);
      }
    }
  __syncthreads();

  {
    const int cb[8] = {0, 128, 512, 640, 256, 384, 768, 896};  // col permute per slab
    const int row = t >> 2, cc = (t & 3) * 32;
    short* outp = G + (size_t)(bm0 + row) * 1024 + cb[y];
    #pragma unroll
    for (int c4 = 0; c4 < 4; ++c4) {
      short8 v = *(const short8*)(Hs + row * 140 + cc + c4 * 8);
      *(short8*)(outp + cc + c4 * 8) = v;
    }
  }
}

// ---------------- K1 (R16-proven): h1_node only, LDS-free direct-A ----------------
__global__ __launch_bounds__(256) void k1_gemm(
    const short* __restrict__ latent_hf, const short* __restrict__ pos_hf,
    const int* __restrict__ batch, const short* __restrict__ Wtcat,
    short* __restrict__ h1_node)
{
  __shared__ short Hs[64 * 140];
  const int t = threadIdx.x;
  const int bm0 = blockIdx.x * 64;
  const int y = blockIdx.y;                    // 0,1
  const int n0 = y * 128;
  const int wid = t >> 6, lane = t & 63;
  const int wm = wid >> 1, wn = wid & 1;
  const int lrow = lane & 15, kq = lane >> 4;
  const half8 hz = {0, 0, 0, 0, 0, 0, 0, 0};

  const int row0 = bm0 + wm * 32 + lrow;
  const int row1 = row0 + 16;
  const int g0 = (row0 < NNODES) ? batch[row0] : 0;
  const int g1 = (row1 < NNODES) ? batch[row1] : 0;

  f4 acc[2][4];
  #pragma unroll
  for (int a = 0; a < 2; ++a)
    #pragma unroll
    for (int b = 0; b < 4; ++b) acc[a][b] = (f4){0.f, 0.f, 0.f, 0.f};

  #pragma unroll
  for (int kc = 0; kc < 9; ++kc) {
    half8 a0, a1;
    if (kc < 8) {
      a0 = *(const half8*)(latent_hf + g0 * 256 + kc * 32 + kq * 8);
      a1 = *(const half8*)(latent_hf + g1 * 256 + kc * 32 + kq * 8);
    } else {
      a0 = hz; a1 = hz;
      if (kq == 0) {
        if (row0 < NNODES) a0 = *(const half8*)(pos_hf + row0 * 8);
        if (row1 < NNODES) a1 = *(const half8*)(pos_hf + row1 * 8);
      } else if (kq == 1) {
        a0[0] = (_Float16)1.0f;
        a1[0] = (_Float16)1.0f;
      }
    }
    #pragma unroll
    for (int nf = 0; nf < 4; ++nf) {
      const int ncol = n0 + wn * 64 + nf * 16 + lrow;
      half8 bfv = *(const half8*)(Wtcat + ncol * 288 + kc * 32 + kq * 8);
      acc[0][nf] = __builtin_amdgcn_mfma_f32_16x16x32_f16(a0, bfv, acc[0][nf], 0, 0, 0);
      acc[1][nf] = __builtin_amdgcn_mfma_f32_16x16x32_f16(a1, bfv, acc[1][nf], 0, 0, 0);
    }
  }

  #pragma unroll
  for (int mf = 0; mf < 2; ++mf)
    #pragma unroll
    for (int nf = 0; nf < 4; ++nf) {
      const int ncol = wn * 64 + nf * 16 + lrow;
      #pragma unroll
      for (int r = 0; r < 4; ++r) {
        const int mrow = wm * 32 + mf * 16 + kq * 4 + r;
        float v = acc[mf][nf][r];
        if (v < 0.f) v = 0.f;
        Hs[mrow * 140 + ncol] = f2h(v);
      }
    }
  __syncthreads();

  {
    const int row = t >> 2, cc = (t & 3) * 32;
    const int m = bm0 + row;
    if (m < NNODES) {
      short* outp = h1_node + (size_t)m * 256 + y * 128;
      #pragma unroll
      for (int c4 = 0; c4 < 4; ++c4) {
        short8 v = *(const short8*)(Hs + row * 140 + cc + c4 * 8);
        *(short8*)(outp + cc + c4 * 8) = v;
      }
    }
  }
}

// ---------------- K23: k3 gathers from L2-resident G; pos A from sequential pose tables ----------------
__global__ __launch_bounds__(256) void k23_fused(
    const short* __restrict__ G,
    const int* __restrict__ ges, const int* __restrict__ ged,
    const short* __restrict__ poseS, const short* __restrict__ poseD,
    const short* __restrict__ Wpos,
    const short* __restrict__ Wt2cat, const short* __restrict__ Wt3t, const short* __restrict__ Wt3d,
    const float* __restrict__ tb2, const float* __restrict__ tb3,
    const float* __restrict__ db2, const float* __restrict__ db3,
    float* __restrict__ out_t, float* __restrict__ out_d,
    const short* __restrict__ h1_node, const short* __restrict__ Wt3n,
    const float* __restrict__ nb2, const float* __restrict__ nb3,
    float* __restrict__ out_node)
{
  __shared__ short smem[32 * 520];             // 33,280 B
  const int t = threadIdx.x;
  const int wid = t >> 6, lane = t & 63;
  const int lrow = lane & 15, kq = lane >> 4;
  const half8 hz = {0, 0, 0, 0, 0, 0, 0, 0};

  const int grp = blockIdx.x / 9, rem = blockIdx.x % 9;

  if (rem != 8) {
    // ================= k3: edge tail =================
    const int tile = grp * 8 + rem;
    if (tile >= K3_BLOCKS) return;
    short* h1 = smem;
    const int e0 = tile * 32;
    const int er = t >> 3, j = t & 7;          // gather coords

    // hoisted sequential index loads (in flight through the pos phase)
    const int s_g = ges[e0 + er];
    const int d_g = ged[e0 + er];

    // ---- pos-part MFMA: A = [pos_s | pos_d | 1 | 0] (K=32) from SEQUENTIAL pose tables ----
    #pragma unroll
    for (int eh = 0; eh < 2; ++eh) {
      half8 av = hz;
      const int e = e0 + eh * 16 + lrow;
      if (kq == 0)      av = *(const half8*)(poseS + (size_t)e * 8);
      else if (kq == 1) av = *(const half8*)(poseD + (size_t)e * 8);
      else if (kq == 2) av[0] = (_Float16)1.0f;
      #pragma unroll
      for (int nf = 0; nf < 8; ++nf) {
        half8 bfv = *(const half8*)(Wpos + (wid * 128 + nf * 16 + lrow) * 32 + kq * 8);
        f4 pa = (f4){0.f, 0.f, 0.f, 0.f};
        pa = __builtin_amdgcn_mfma_f32_16x16x32_f16(av, bfv, pa, 0, 0, 0);
        #pragma unroll
        for (int r = 0; r < 4; ++r)
          h1[(eh * 16 + kq * 4 + r) * 520 + wid * 128 + nf * 16 + lrow] = f2h(pa[r]);
      }
    }
    __syncthreads();                           // pos parts ready

    // ---- gather from G (L2-hot) + combine with pos ----
    {
      const short* Ps = G + (size_t)s_g * 1024 + j * 8;
      const short* Pd = G + (size_t)d_g * 1024 + 512 + j * 8;
      short8 sv[8], dv[8];
      #pragma unroll
      for (int c = 0; c < 8; ++c) sv[c] = *(const short8*)(Ps + c * 64);
      #pragma unroll
      for (int c = 0; c < 8; ++c) dv[c] = *(const short8*)(Pd + c * 64);
      #pragma unroll
      for (int c = 0; c < 8; ++c) {
        short8 pv = *(const short8*)(h1 + er * 520 + c * 64 + j * 8);
        half8 a = __builtin_bit_cast(half8, sv[c]);
        half8 b = __builtin_bit_cast(half8, dv[c]);
        half8 p = __builtin_bit_cast(half8, pv);
        half8 o = __builtin_elementwise_max(a + b + p, hz);
        *(short8*)(h1 + er * 520 + c * 64 + j * 8) = __builtin_bit_cast(short8, o);
      }
    }
    __syncthreads();

    // ---- layer2 TYPE ----
    f4 acc_t[2][2];
    #pragma unroll
    for (int a = 0; a < 2; ++a)
      #pragma unroll
      for (int b = 0; b < 2; ++b) acc_t[a][b] = (f4){0.f, 0.f, 0.f, 0.f};
    #pragma unroll
    for (int kc = 0; kc < 8; ++kc) {
      half8 a0 = *(const half8*)(h1 + lrow * 520 + kc * 32 + kq * 8);
      half8 a1 = *(const half8*)(h1 + (16 + lrow) * 520 + kc * 32 + kq * 8);
      #pragma unroll
      for (int nf = 0; nf < 2; ++nf) {
        half8 bfv = *(const half8*)(Wt2cat + (128 + wid * 32 + nf * 16 + lrow) * 256 + kc * 32 + kq * 8);
        acc_t[0][nf] = __builtin_amdgcn_mfma_f32_16x16x32_f16(a0, bfv, acc_t[0][nf], 0, 0, 0);
        acc_t[1][nf] = __builtin_amdgcn_mfma_f32_16x16x32_f16(a1, bfv, acc_t[1][nf], 0, 0, 0);
      }
    }
    __syncthreads();

    // ---- h2_t -> cols 0:128 ----
    #pragma unroll
    for (int mf = 0; mf < 2; ++mf)
      #pragma unroll
      for (int nf = 0; nf < 2; ++nf) {
        const int n2 = wid * 32 + nf * 16 + lrow;
        const float bb = tb2[n2];
        #pragma unroll
        for (int rr = 0; rr < 4; ++rr) {
          float h = acc_t[mf][nf][rr] + bb;
          h1[(mf * 16 + kq * 4 + rr) * 520 + n2] = f2h(h > 0.f ? h : 0.f);
        }
      }

    // ---- layer2 DIR ----
    f4 acc_d[2][2];
    #pragma unroll
    for (int a = 0; a < 2; ++a)
      #pragma unroll
      for (int b = 0; b < 2; ++b) acc_d[a][b] = (f4){0.f, 0.f, 0.f, 0.f};
    #pragma unroll
    for (int kc = 0; kc < 8; ++kc) {
      half8 a0 = *(const half8*)(h1 + lrow * 520 + 256 + kc * 32 + kq * 8);
      half8 a1 = *(const half8*)(h1 + (16 + lrow) * 520 + 256 + kc * 32 + kq * 8);
      #pragma unroll
      for (int nf = 0; nf < 2; ++nf) {
        half8 bfv = *(const half8*)(Wt2cat + (256 + wid * 32 + nf * 16 + lrow) * 256 + kc * 32 + kq * 8);
        acc_d[0][nf] = __builtin_amdgcn_mfma_f32_16x16x32_f16(a0, bfv, acc_d[0][nf], 0, 0, 0);
        acc_d[1][nf] = __builtin_amdgcn_mfma_f32_16x16x32_f16(a1, bfv, acc_d[1][nf], 0, 0, 0);
      }
    }

    // ---- h2_d -> cols 128:256 ----
    #pragma unroll
    for (int mf = 0; mf < 2; ++mf)
      #pragma unroll
      for (int nf = 0; nf < 2; ++nf) {
        const int n2 = wid * 32 + nf * 16 + lrow;
        const float bb = db2[n2];
        #pragma unroll
        for (int rr = 0; rr < 4; ++rr) {
          float h = acc_d[mf][nf][rr] + bb;
          h1[(mf * 16 + kq * 4 + rr) * 520 + 128 + n2] = f2h(h > 0.f ? h : 0.f);
        }
      }
    __syncthreads();

    // ---- layer 3 via MFMA ----
    {
      const int mlp3 = wid >> 1, mh = wid & 1;
      const int ncols = mlp3 ? 3 : 4;
      const short* W3 = mlp3 ? Wt3d : Wt3t;
      f4 acc3 = (f4){0.f, 0.f, 0.f, 0.f};
      #pragma unroll
      for (int kc = 0; kc < 4; ++kc) {
        half8 af = *(const half8*)(h1 + (mh * 16 + lrow) * 520 + mlp3 * 128 + kc * 32 + kq * 8);
        half8 bfv = hz;
        if (lrow < ncols) bfv = *(const half8*)(W3 + lrow * 128 + kc * 32 + kq * 8);
        acc3 = __builtin_amdgcn_mfma_f32_16x16x32_f16(af, bfv, acc3, 0, 0, 0);
      }
      if (lrow < ncols) {
        const float bb = (mlp3 ? db3 : tb3)[lrow];
        float* outp = mlp3 ? out_d : out_t;
        #pragma unroll
        for (int r = 0; r < 4; ++r) {
          const int e = e0 + mh * 16 + kq * 4 + r;
          outp[(size_t)e * ncols + lrow] = acc3[r] + bb;
        }
      }
    }
  } else {
    // ================= k2: node tail (unchanged) =================
    short* h2s = smem;
    const int bm0 = grp * 64;
    const int wm = wid >> 1, wn = wid & 1;

    f4 acc[2][4];
    #pragma unroll
    for (int a = 0; a < 2; ++a)
      #pragma unroll
      for (int b = 0; b < 4; ++b) acc[a][b] = (f4){0.f, 0.f, 0.f, 0.f};

    #pragma unroll
    for (int kc = 0; kc < 8; ++kc) {
      half8 af[2];
      #pragma unroll
      for (int mf = 0; mf < 2; ++mf) {
        const int m = bm0 + wm * 32 + mf * 16 + lrow;
        if (m < NNODES) af[mf] = *(const half8*)(h1_node + m * 256 + kc * 32 + kq * 8);
        else            af[mf] = (half8){0, 0, 0, 0, 0, 0, 0, 0};
      }
      #pragma unroll
      for (int nf = 0; nf < 4; ++nf) {
        const int ncol = wn * 64 + nf * 16 + lrow;
        half8 bfv = *(const half8*)(Wt2cat + ncol * 256 + kc * 32 + kq * 8);
        acc[0][nf] = __builtin_amdgcn_mfma_f32_16x16x32_f16(af[0], bfv, acc[0][nf], 0, 0, 0);
        acc[1][nf] = __builtin_amdgcn_mfma_f32_16x16x32_f16(af[1], bfv, acc[1][nf], 0, 0, 0);
      }
    }
    #pragma unroll
    for (int mf = 0; mf < 2; ++mf)
      #pragma unroll
      for (int nf = 0; nf < 4; ++nf) {
        const int n = wn * 64 + nf * 16 + lrow;
        #pragma unroll
        for (int r = 0; r < 4; ++r) {
          const int ml = wm * 32 + mf * 16 + kq * 4 + r;
          float h = acc[mf][nf][r] + nb2[n];
          h2s[ml * 136 + n] = f2h(h > 0.f ? h : 0.f);
        }
      }
    __syncthreads();

    f4 acc2[2][4];
    #pragma unroll
    for (int a = 0; a < 2; ++a)
      #pragma unroll
      for (int b = 0; b < 4; ++b) acc2[a][b] = (f4){0.f, 0.f, 0.f, 0.f};

    #pragma unroll
    for (int kc = 0; kc < 4; ++kc) {
      half8 af[2];
      #pragma unroll
      for (int mf = 0; mf < 2; ++mf)
        af[mf] = *(const half8*)(h2s + (wm * 32 + mf * 16 + lrow) * 136 + kc * 32 + kq * 8);
      #pragma unroll
      for (int nf = 0; nf < 4; ++nf) {
        const int ncol = wn * 64 + nf * 16 + lrow;
        half8 bfv = *(const half8*)(Wt3n + ncol * 128 + kc * 32 + kq * 8);
        acc2[0][nf] = __builtin_amdgcn_mfma_f32_16x16x32_f16(af[0], bfv, acc2[0][nf], 0, 0, 0);
        acc2[1][nf] = __builtin_amdgcn_mfma_f32_16x16x32_f16(af[1], bfv, acc2[1][nf], 0, 0, 0);
      }
    }
    #pragma unroll
    for (int mf = 0; mf < 2; ++mf)
      #pragma unroll
      for (int nf = 0; nf < 4; ++nf) {
        const int n = wn * 64 + nf * 16 + lrow;
        #pragma unroll
        for (int r = 0; r < 4; ++r) {
          const int m = bm0 + wm * 32 + mf * 16 + kq * 4 + r;
          if (m < NNODES && n < NT) out_node[m * NT + n] = acc2[mf][nf][r] + nb3[n];
        }
      }
  }
}

extern "C" void kernel_launch(void* const* d_in, const int* in_sizes, int n_in,
                              void* d_out, int out_size, void* d_ws, size_t ws_size,
                              hipStream_t stream)
{
  const float* lat = (const float*)d_in[0];
  const float* pos = (const float*)d_in[1];
  const int* batch = (const int*)d_in[2];
  const int* eidx  = (const int*)d_in[3];
  const float* nW1 = (const float*)d_in[4];  const float* nb1 = (const float*)d_in[5];
  const float* nW2 = (const float*)d_in[6];  const float* nb2 = (const float*)d_in[7];
  const float* nW3 = (const float*)d_in[8];  const float* nb3 = (const float*)d_in[9];
  const float* tW1 = (const float*)d_in[10]; const float* tb1 = (const float*)d_in[11];
  const float* tW2 = (const float*)d_in[12]; const float* tb2 = (const float*)d_in[13];
  const float* tW3 = (const float*)d_in[14]; const float* tb3 = (const float*)d_in[15];
  const float* dW1 = (const float*)d_in[16]; const float* db1 = (const float*)d_in[17];
  const float* dW2 = (const float*)d_in[18]; const float* db2 = (const float*)d_in[19];
  const float* dW3 = (const float*)d_in[20]; const float* db3 = (const float*)d_in[21];

  char* ws = (char*)d_ws;
  short* latent_hf = (short*)(ws + 0);          //  1,048,576 B
  short* pos_hf    = (short*)(ws + 1048576);    //  1,600,000 B
  short* Wtcat     = (short*)(ws + 2648576);    //    737,280 B
  short* Wt2cat    = (short*)(ws + 3385856);    //    196,608 B
  short* Wt3n      = (short*)(ws + 3582464);    //     32,768 B
  short* Wt3t      = (short*)(ws + 3615232);    //      1,024 B
  short* Wt3d      = (short*)(ws + 3616256);    //      1,024 B
  short* Wpos      = (short*)(ws + 3617280);    //     32,768 B
  short* h1_node   = (short*)(ws + 3650048);    // 51,200,000 B
  int*   ges       = (int*)(ws + 54850048);     //  1,600,000 B
  int*   ged       = (int*)(ws + 56450048);     //  1,600,000 B
  short* G         = (short*)(ws + 58050048);   //  4,194,304 B
  short* poseS     = (short*)(ws + 62244352);   //  6,400,000 B
  short* poseD     = (short*)(ws + 68644352);   //  6,400,000 B -> total ~75.0 MB

  float* out_node = (float*)d_out;
  float* out_t = out_node + (size_t)NNODES * NT;
  float* out_d = out_t + (size_t)NEDGES * 4;

  prep_kernel<<<7129, 256, 0, stream>>>(lat, pos, nW1, tW1, dW1, nW2, tW2, dW2,
                                        nW3, tW3, dW3, nb1, tb1, db1,
                                        latent_hf, pos_hf, Wtcat,
                                        Wt2cat, Wt3n, Wt3t, Wt3d, Wpos);
  kge<<<1563, 256, 0, stream>>>(eidx, batch, pos_hf, ges, ged, poseS, poseD);
  kG<<<dim3(32, 8), 256, 0, stream>>>(latent_hf, Wtcat, G);
  k1_gemm<<<dim3(1563, 2), 256, 0, stream>>>(latent_hf, pos_hf, batch, Wtcat, h1_node);
  k23_fused<<<K2_BLOCKS * 9, 256, 0, stream>>>(
      G, ges, ged, poseS, poseD, Wpos, Wt2cat, Wt3t, Wt3d, tb2, tb3, db2, db3,
      out_t, out_d, h1_node, Wt3n, nb2, nb3, out_node);
}